// Round 1
// baseline (1972.323 us; speedup 1.0000x reference)
//
#include <hip/hip_runtime.h>
#include <cmath>

#define DEV __device__ __forceinline__

static DEV float leakyf(float x){ return x >= 0.0f ? x : 0.2f*x; }

// ---------------- Dopri5 tableau (double-computed, rounded to f32 like jax weak typing) ----
constexpr float cA21 = (float)(1.0/5.0);
constexpr float cA31 = (float)(3.0/40.0),  cA32 = (float)(9.0/40.0);
constexpr float cA41 = (float)(44.0/45.0), cA42 = (float)(-56.0/15.0), cA43 = (float)(32.0/9.0);
constexpr float cA51 = (float)(19372.0/6561.0), cA52 = (float)(-25360.0/2187.0);
constexpr float cA53 = (float)(64448.0/6561.0), cA54 = (float)(-212.0/729.0);
constexpr float cA61 = (float)(9017.0/3168.0),  cA62 = (float)(-355.0/33.0);
constexpr float cA63 = (float)(46732.0/5247.0), cA64 = (float)(49.0/176.0);
constexpr float cA65 = (float)(-5103.0/18656.0);
constexpr float cB1 = (float)(35.0/384.0),  cB3 = (float)(500.0/1113.0), cB4 = (float)(125.0/192.0);
constexpr float cB5 = (float)(-2187.0/6784.0), cB6 = (float)(11.0/84.0);
constexpr float cE1 = (float)(71.0/57600.0), cE3 = (float)(-71.0/16695.0), cE4 = (float)(71.0/1920.0);
constexpr float cE5 = (float)(-17253.0/339200.0), cE6 = (float)(22.0/525.0), cE7 = (float)(-1.0/40.0);

// ---------------- workspace layout (float indices into d_ws) ----------------
#define WS_AMAT   0                      // 256 floats   : A(p) 16x16 (leaky applied)
#define WS_HB3    256                    // 2048 floats  : B-net hidden 3
#define WS_BTEN   2304                   // 4096 floats  : B(p) 16x16x16 (leaky applied)
#define WS_ZS     6400                   // 32*2048*16 = 1048576 floats : z trajectory
#define WS_SLOTSF (6400 + 1048576)       // 496*256 u64 barrier slots = 253952 floats
#define WS_W2T    (WS_SLOTSF + 253952)   // 466*96 floats : transposed+padded Wd2
// total ~5.42 MB of workspace

// ================= K1: tiny MLPs (A-net fully; B-net through hb3) — 1 block ==========
__global__ void __launch_bounds__(256) k_smallnets(
    const float* __restrict__ p,
    const float* __restrict__ Wa1, const float* __restrict__ ba1,
    const float* __restrict__ Wa2, const float* __restrict__ ba2,
    const float* __restrict__ Wa3, const float* __restrict__ ba3,
    const float* __restrict__ Wb1, const float* __restrict__ bb1,
    const float* __restrict__ Wb2, const float* __restrict__ bb2,
    const float* __restrict__ Wb3, const float* __restrict__ bb3,
    float* __restrict__ wsf)
{
    __shared__ float sp[4], sa1[16], sa2[128], sb1[16], sb2[64];
    int tid = threadIdx.x;
    if (tid < 4) sp[tid] = p[tid];
    __syncthreads();
    if (tid < 16) {
        float a = ba1[tid];
        for (int j = 0; j < 4; ++j) a = fmaf(sp[j], Wa1[j*16+tid], a);
        sa1[tid] = leakyf(a);
        float c = bb1[tid];
        for (int j = 0; j < 4; ++j) c = fmaf(sp[j], Wb1[j*16+tid], c);
        sb1[tid] = leakyf(c);
    }
    __syncthreads();
    if (tid < 128) {
        float a = ba2[tid];
        for (int j = 0; j < 16; ++j) a = fmaf(sa1[j], Wa2[j*128+tid], a);
        sa2[tid] = leakyf(a);
    }
    if (tid < 64) {
        float c = bb2[tid];
        for (int j = 0; j < 16; ++j) c = fmaf(sb1[j], Wb2[j*64+tid], c);
        sb2[tid] = leakyf(c);
    }
    __syncthreads();
    {   // Amat: 256 outputs
        float a = ba3[tid];
        for (int j = 0; j < 128; ++j) a = fmaf(sa2[j], Wa3[j*256+tid], a);
        wsf[WS_AMAT + tid] = leakyf(a);
    }
    for (int q = 0; q < 8; ++q) {        // hb3: 2048 outputs
        int o = q*256 + tid;
        float c = bb3[o];
        for (int j = 0; j < 64; ++j) c = fmaf(sb2[j], Wb3[j*2048+o], c);
        wsf[WS_HB3 + o] = leakyf(c);
    }
}

// ================= K2: Bten = leaky(hb3 @ Wb4 + bb4) — HBM-bound (33.5 MB) ==========
__global__ void __launch_bounds__(256) k_bten(
    const float* __restrict__ Wb4, const float* __restrict__ bb4, float* __restrict__ wsf)
{
    __shared__ float red[256];
    const float* hb3 = wsf + WS_HB3;
    float* Bten = wsf + WS_BTEN;
    int tid = threadIdx.x;
    int ol = tid & 15, part = tid >> 4;          // 16 outputs/block, 16 hh-parts of 128
    int o = blockIdx.x * 16 + ol;
    float a = 0.0f;
    for (int q = 0; q < 128; ++q) {
        int hh = part*128 + q;
        a = fmaf(hb3[hh], Wb4[(size_t)hh*4096 + o], a);
    }
    red[part*16 + ol] = a;
    __syncthreads();
    for (int s = 8; s >= 1; s >>= 1) {
        if (part < s) red[part*16+ol] += red[(part+s)*16+ol];
        __syncthreads();
    }
    if (tid < 16) {
        float v = red[tid] + bb4[blockIdx.x*16 + tid];
        Bten[blockIdx.x*16 + tid] = leakyf(v);
    }
}

// ================= K3: encoder -> zs slab 0 (z0) =====================================
__global__ void __launch_bounds__(256) k_encoder(
    const float* __restrict__ n0,
    const float* __restrict__ We1, const float* __restrict__ be1,
    const float* __restrict__ We2, const float* __restrict__ be2,
    float* __restrict__ zs)
{
    __shared__ float hL[8][88];
    int tid = threadIdx.x;
    int r = tid >> 5, c = tid & 31;
    int row = blockIdx.x * 8 + r;
    const float* nrow = n0 + (size_t)row * 466;
    int c2 = (c + 64 < 86) ? (c + 64) : 85;      // clamp (discarded if invalid)
    float a0 = 0.f, a1 = 0.f, a2 = 0.f;
    for (int n = 0; n < 466; ++n) {
        float nv = nrow[n];
        a0 = fmaf(nv, We1[n*86 + c], a0);
        a1 = fmaf(nv, We1[n*86 + c + 32], a1);
        a2 = fmaf(nv, We1[n*86 + c2], a2);
    }
    hL[r][c]      = leakyf(a0 + be1[c]);
    hL[r][c + 32] = leakyf(a1 + be1[c + 32]);
    if (c < 22) hL[r][c + 64] = leakyf(a2 + be1[c + 64]);
    __syncthreads();
    if (tid < 128) {
        int r2 = tid >> 4, ii = tid & 15;
        int row2 = blockIdx.x * 8 + r2;
        float a = be2[ii];
        #pragma unroll
        for (int hh = 0; hh < 86; ++hh) a = fmaf(hL[r2][hh], We2[hh*16 + ii], a);
        zs[(size_t)row2 * 16 + ii] = a;          // NO leaky on z0
    }
}

// ================= K3b: transpose+pad Wd2 [86,466] -> [466,96] for s_load_dwordx8 ====
__global__ void k_w2t(const float* __restrict__ Wd2, float* __restrict__ Wd2P)
{
    int c = blockIdx.x * 256 + threadIdx.x;
    if (c < 466) {
        for (int hh = 0; hh < 86; ++hh) Wd2P[c*96 + hh] = Wd2[hh*466 + c];
    }
}

// ================= K4: cooperative Dopri5 solver =====================================
// 256 blocks x 256 threads. 2 threads per (batch b, component i): h in {0,1} owns the
// k-half h*8..h*8+7 of B[i][:][:] in 128 VGPRs (loaded once, reused ~all steps).
// Per trial step: 6 f-evals (FSAL: k1 carried), then one decentralized grid barrier:
// each block stores {flag|partial} as one 64-bit agent-scope word into slot[step][blk];
// every block polls all 256 slots and reduces them in a fixed order -> bit-identical en
// in every block -> identical accept/dt control flow (no divergence between blocks).
// NaN(en) is a proven fixed point of the reference controller -> fill remaining slabs
// with frozen y and exit.
__global__ void __launch_bounds__(256) k_solver(
    const float* __restrict__ tstep, float* __restrict__ wsf)
{
    __shared__ float zL[8][16];
    __shared__ float redA[4], redB[4];
    float* Amat = wsf + WS_AMAT;
    float* Bten = wsf + WS_BTEN;
    float* zs   = wsf + WS_ZS;
    unsigned long long* slots = (unsigned long long*)(wsf + WS_SLOTSF);

    const int tid = threadIdx.x, blk = blockIdx.x;
    const int e = tid >> 5, g = tid & 31;
    const int i = g >> 1, h = g & 1, h8 = h * 8;
    const int b = blk * 8 + e;

    // --- load per-thread constants: B half-slice + A row (h0 only) ---
    float Bl[128], aR[16];
    #pragma unroll
    for (int jj = 0; jj < 16; ++jj) {
        int j = (h8 + jj) & 15;                      // per-thread j iteration order
        aR[jj] = (h == 0) ? Amat[i*16 + jj] : 0.0f;  // h0: h8=0 -> j==jj
        const float4* bp = (const float4*)(Bten + i*256 + j*16 + h8);
        float4 b0 = bp[0], b1 = bp[1];
        Bl[jj*8+0]=b0.x; Bl[jj*8+1]=b0.y; Bl[jj*8+2]=b0.z; Bl[jj*8+3]=b0.w;
        Bl[jj*8+4]=b1.x; Bl[jj*8+5]=b1.y; Bl[jj*8+6]=b1.z; Bl[jj*8+7]=b1.w;
    }

    float y = zs[(size_t)b*16 + i];

    // f_i(z) = sum_j A_ij z_j + sum_jk B_ijk z_j z_k ; each thread computes its half,
    // combined across the h-pair by one shfl_xor. Stage vector exchanged via wave-local
    // LDS (same-wave write->read, in-order DS pipe, no barrier needed).
    auto feval = [&](float zi) -> float {
        zL[e][i] = zi;                                // both h lanes write same value
        const float4* zp = (const float4*)(&zL[e][0]);
        int q0 = h8 >> 2;                             // 0 or 2: rotated read -> zz[m]=z[(h8+m)&15]
        float4 r0 = zp[q0], r1 = zp[(q0+1)&3], r2 = zp[(q0+2)&3], r3 = zp[(q0+3)&3];
        float zz[16] = { r0.x,r0.y,r0.z,r0.w, r1.x,r1.y,r1.z,r1.w,
                         r2.x,r2.y,r2.z,r2.w, r3.x,r3.y,r3.z,r3.w };
        float acc = 0.0f;
        #pragma unroll
        for (int jj = 0; jj < 16; ++jj) {
            float tmp = aR[jj];
            #pragma unroll
            for (int kk = 0; kk < 8; ++kk) tmp = fmaf(Bl[jj*8+kk], zz[kk], tmp);
            acc = fmaf(zz[jj], tmp, acc);
        }
        acc += __shfl_xor(acc, 1);                    // combine the two k-halves
        return acc;
    };

    float dt = (tstep[1] - tstep[0]) * 0.3f;
    float k1 = feval(y), k2, k3, k4, k5, k6, k7;
    int stepIdx = 0;

    for (int iv = 0; iv < 31; ++iv) {
        float t  = tstep[iv];
        float t1 = tstep[iv + 1];
        for (int it = 0; it < 16; ++it) {
            if (t >= t1 - 1e-10f) break;              // 'done' iterations are exact no-ops
            float dtc = fminf(dt, t1 - t);

            float z2 = fmaf(dtc, cA21*k1, y);                                         k2 = feval(z2);
            float z3 = fmaf(dtc, fmaf(cA32,k2, cA31*k1), y);                          k3 = feval(z3);
            float z4 = fmaf(dtc, fmaf(cA43,k3, fmaf(cA42,k2, cA41*k1)), y);           k4 = feval(z4);
            float z5 = fmaf(dtc, fmaf(cA54,k4, fmaf(cA53,k3, fmaf(cA52,k2, cA51*k1))), y);
            k5 = feval(z5);
            float z6 = fmaf(dtc, fmaf(cA65,k5, fmaf(cA64,k4, fmaf(cA63,k3, fmaf(cA62,k2, cA61*k1)))), y);
            k6 = feval(z6);
            float y5 = fmaf(dtc, fmaf(cB6,k6, fmaf(cB5,k5, fmaf(cB4,k4, fmaf(cB3,k3, cB1*k1)))), y);
            k7 = feval(y5);
            float err = dtc * fmaf(cE7,k7, fmaf(cE6,k6, fmaf(cE5,k5, fmaf(cE4,k4, fmaf(cE3,k3, cE1*k1)))));

            float ay = fabsf(y), a5 = fabsf(y5);
            float mx = (ay > a5) ? ay : a5;           // NaN-propagating max (matches jnp)
            float tol = fmaf(1e-5f, mx, 1e-20f);
            float r = err / tol;
            float r2 = r * r;

            // ---- block partial sum (h-duplicated; divide by 65536 at the end) ----
            float w = r2;
            w += __shfl_xor(w, 1);  w += __shfl_xor(w, 2);  w += __shfl_xor(w, 4);
            w += __shfl_xor(w, 8);  w += __shfl_xor(w, 16); w += __shfl_xor(w, 32);
            if ((tid & 63) == 0) redA[tid >> 6] = w;
            __syncthreads();
            float bsum = ((redA[0] + redA[1]) + redA[2]) + redA[3];
            __syncthreads();

            // ---- decentralized grid barrier: value-carrying 64-bit slots ----
            unsigned long long* rowp = slots + (size_t)stepIdx * 256;
            if (tid == 0) {
                unsigned long long pv = (1ull << 32) | (unsigned long long)__float_as_uint(bsum);
                __hip_atomic_store(&rowp[blk], pv, __ATOMIC_RELAXED, __HIP_MEMORY_SCOPE_AGENT);
            }
            unsigned long long v;
            for (;;) {
                v = __hip_atomic_load(&rowp[tid], __ATOMIC_RELAXED, __HIP_MEMORY_SCOPE_AGENT);
                if ((unsigned)(v >> 32) == 1u) break;
                __builtin_amdgcn_s_sleep(2);
            }
            float ps = __uint_as_float((unsigned)v);
            ps += __shfl_xor(ps, 1);  ps += __shfl_xor(ps, 2);  ps += __shfl_xor(ps, 4);
            ps += __shfl_xor(ps, 8);  ps += __shfl_xor(ps, 16); ps += __shfl_xor(ps, 32);
            if ((tid & 63) == 0) redB[tid >> 6] = ps;
            __syncthreads();
            float gsum = ((redB[0] + redB[1]) + redB[2]) + redB[3];
            __syncthreads();
            ++stepIdx;

            float en = sqrtf(gsum * (1.0f / 65536.0f));   // /65536: h-dup (x2) * mean (/32768)

            if (!(en == en)) {
                // NaN controller state is a fixed point of the reference: y frozen forever.
                if (h == 0) {
                    for (int s = iv + 1; s < 32; ++s)
                        zs[((size_t)s * 2048 + b) * 16 + i] = y;
                }
                return;
            }
            if (en <= 1.0f) { t = t + dtc; y = y5; k1 = k7; }   // accept (+FSAL)
            float fac = 0.9f * powf(fmaxf(en, 1e-12f), -0.2f);
            fac = fminf(fmaxf(fac, 0.2f), 10.0f);
            dt = dt * fac;
        }
        if (h == 0) zs[((size_t)(iv + 1) * 2048 + b) * 16 + i] = y;
    }
}

// ================= K5: decoder  out = leaky(zs@Wd1+bd1)@Wd2 + bd2 ====================
// thread-per-row, h[86] in registers; Wd2 pre-transposed/padded -> wave-uniform
// s_load_dwordx8 stream in the inner product. hf (column half) uniform per block.
__global__ void __launch_bounds__(256) k_decoder(
    const float* __restrict__ zs,
    const float* __restrict__ Wd1, const float* __restrict__ bd1,
    const float* __restrict__ Wd2P, const float* __restrict__ bd2,
    float* __restrict__ out)
{
    int hf = blockIdx.x >> 8;                     // 0..1 (wave-uniform)
    int rowblk = blockIdx.x & 255;
    int rr = rowblk * 256 + threadIdx.x;          // 0..65535

    const float4* zp = (const float4*)(zs + (size_t)rr * 16);
    float4 za = zp[0], zb = zp[1], zc = zp[2], zd = zp[3];
    float z[16] = { za.x,za.y,za.z,za.w, zb.x,zb.y,zb.z,zb.w,
                    zc.x,zc.y,zc.z,zc.w, zd.x,zd.y,zd.z,zd.w };

    float hreg[86];
    #pragma unroll
    for (int hh = 0; hh < 86; ++hh) {
        float a = bd1[hh];
        #pragma unroll
        for (int ii = 0; ii < 16; ++ii) a = fmaf(z[ii], Wd1[ii*86 + hh], a);
        hreg[hh] = leakyf(a);
    }

    int c0 = hf * 233, c1 = c0 + 233;
    float* orow = out + (size_t)rr * 466;
    for (int c = c0; c < c1; ++c) {
        const float* wrow = Wd2P + c * 96;        // 32B-aligned, wave-uniform
        float a = bd2[c];
        #pragma unroll
        for (int hh = 0; hh < 86; ++hh) a = fmaf(hreg[hh], wrow[hh], a);
        orow[c] = a;                              // no leaky on final layer
    }
}

// ====================================================================================
extern "C" void kernel_launch(void* const* d_in, const int* in_sizes, int n_in,
                              void* d_out, int out_size, void* d_ws, size_t ws_size,
                              hipStream_t stream)
{
    const float* n0   = (const float*)d_in[0];
    const float* p    = (const float*)d_in[1];
    const float* tstep= (const float*)d_in[2];
    const float* We1  = (const float*)d_in[3];  const float* be1 = (const float*)d_in[4];
    const float* We2  = (const float*)d_in[5];  const float* be2 = (const float*)d_in[6];
    const float* Wd1  = (const float*)d_in[7];  const float* bd1 = (const float*)d_in[8];
    const float* Wd2  = (const float*)d_in[9];  const float* bd2 = (const float*)d_in[10];
    const float* Wa1  = (const float*)d_in[11]; const float* ba1 = (const float*)d_in[12];
    const float* Wa2  = (const float*)d_in[13]; const float* ba2 = (const float*)d_in[14];
    const float* Wa3  = (const float*)d_in[15]; const float* ba3 = (const float*)d_in[16];
    const float* Wb1  = (const float*)d_in[17]; const float* bb1 = (const float*)d_in[18];
    const float* Wb2  = (const float*)d_in[19]; const float* bb2 = (const float*)d_in[20];
    const float* Wb3  = (const float*)d_in[21]; const float* bb3 = (const float*)d_in[22];
    const float* Wb4  = (const float*)d_in[23]; const float* bb4 = (const float*)d_in[24];
    float* out = (float*)d_out;
    float* wsf = (float*)d_ws;

    hipLaunchKernelGGL(k_smallnets, dim3(1), dim3(256), 0, stream,
                       p, Wa1, ba1, Wa2, ba2, Wa3, ba3, Wb1, bb1, Wb2, bb2, Wb3, bb3, wsf);
    hipLaunchKernelGGL(k_bten, dim3(256), dim3(256), 0, stream, Wb4, bb4, wsf);
    hipLaunchKernelGGL(k_encoder, dim3(256), dim3(256), 0, stream,
                       n0, We1, be1, We2, be2, wsf + WS_ZS);
    hipLaunchKernelGGL(k_w2t, dim3(2), dim3(256), 0, stream, Wd2, wsf + WS_W2T);

    // cooperative launch guarantees co-residency for the slot-barrier protocol
    void* args[] = { (void*)&tstep, (void*)&wsf };
    hipLaunchCooperativeKernel(k_solver, dim3(256), dim3(256), args, 0, stream);

    hipLaunchKernelGGL(k_decoder, dim3(512), dim3(256), 0, stream,
                       wsf + WS_ZS, Wd1, bd1, wsf + WS_W2T, bd2, out);
}

// Round 2
// 1649.788 us; speedup vs baseline: 1.1955x; 1.1955x over previous
//
#include <hip/hip_runtime.h>
#include <cmath>

#define DEV __device__ __forceinline__

static DEV float leakyf(float x){ return x >= 0.0f ? x : 0.2f*x; }

typedef float v2f __attribute__((ext_vector_type(2)));

// ---------------- Dopri5 tableau ----------------
constexpr float cA21 = (float)(1.0/5.0);
constexpr float cA31 = (float)(3.0/40.0),  cA32 = (float)(9.0/40.0);
constexpr float cA41 = (float)(44.0/45.0), cA42 = (float)(-56.0/15.0), cA43 = (float)(32.0/9.0);
constexpr float cA51 = (float)(19372.0/6561.0), cA52 = (float)(-25360.0/2187.0);
constexpr float cA53 = (float)(64448.0/6561.0), cA54 = (float)(-212.0/729.0);
constexpr float cA61 = (float)(9017.0/3168.0),  cA62 = (float)(-355.0/33.0);
constexpr float cA63 = (float)(46732.0/5247.0), cA64 = (float)(49.0/176.0);
constexpr float cA65 = (float)(-5103.0/18656.0);
constexpr float cB1 = (float)(35.0/384.0),  cB3 = (float)(500.0/1113.0), cB4 = (float)(125.0/192.0);
constexpr float cB5 = (float)(-2187.0/6784.0), cB6 = (float)(11.0/84.0);
constexpr float cE1 = (float)(71.0/57600.0), cE3 = (float)(-71.0/16695.0), cE4 = (float)(71.0/1920.0);
constexpr float cE5 = (float)(-17253.0/339200.0), cE6 = (float)(22.0/525.0), cE7 = (float)(-1.0/40.0);

// ---------------- workspace layout (float indices into d_ws) ----------------
#define WS_AMAT   0                      // 256 floats   : A(p) 16x16 (leaky applied)
#define WS_HB3    256                    // 2048 floats  : B-net hidden 3
#define WS_BTEN   2304                   // 4096 floats  : B(p) 16x16x16 (leaky applied)
#define WS_ZS     6400                   // 32*2048*16 = 1048576 floats : z trajectory
#define WS_SLOTSF (6400 + 1048576)       // 496*256 u64 barrier slots = 253952 floats

// ================= K1: tiny MLPs (A-net fully; B-net through hb3) — 1 block ==========
__global__ void __launch_bounds__(256) k_smallnets(
    const float* __restrict__ p,
    const float* __restrict__ Wa1, const float* __restrict__ ba1,
    const float* __restrict__ Wa2, const float* __restrict__ ba2,
    const float* __restrict__ Wa3, const float* __restrict__ ba3,
    const float* __restrict__ Wb1, const float* __restrict__ bb1,
    const float* __restrict__ Wb2, const float* __restrict__ bb2,
    const float* __restrict__ Wb3, const float* __restrict__ bb3,
    float* __restrict__ wsf)
{
    __shared__ float sp[4], sa1[16], sa2[128], sb1[16], sb2[64];
    int tid = threadIdx.x;
    if (tid < 4) sp[tid] = p[tid];
    __syncthreads();
    if (tid < 16) {
        float a = ba1[tid];
        for (int j = 0; j < 4; ++j) a = fmaf(sp[j], Wa1[j*16+tid], a);
        sa1[tid] = leakyf(a);
        float c = bb1[tid];
        for (int j = 0; j < 4; ++j) c = fmaf(sp[j], Wb1[j*16+tid], c);
        sb1[tid] = leakyf(c);
    }
    __syncthreads();
    if (tid < 128) {
        float a = ba2[tid];
        for (int j = 0; j < 16; ++j) a = fmaf(sa1[j], Wa2[j*128+tid], a);
        sa2[tid] = leakyf(a);
    }
    if (tid < 64) {
        float c = bb2[tid];
        for (int j = 0; j < 16; ++j) c = fmaf(sb1[j], Wb2[j*64+tid], c);
        sb2[tid] = leakyf(c);
    }
    __syncthreads();
    {   // Amat: 256 outputs
        float a = ba3[tid];
        for (int j = 0; j < 128; ++j) a = fmaf(sa2[j], Wa3[j*256+tid], a);
        wsf[WS_AMAT + tid] = leakyf(a);
    }
    for (int q = 0; q < 8; ++q) {        // hb3: 2048 outputs
        int o = q*256 + tid;
        float c = bb3[o];
        for (int j = 0; j < 64; ++j) c = fmaf(sb2[j], Wb3[j*2048+o], c);
        wsf[WS_HB3 + o] = leakyf(c);
    }
}

// ================= K2: Bten = leaky(hb3 @ Wb4 + bb4) — HBM-bound (33.5 MB) ==========
__global__ void __launch_bounds__(256) k_bten(
    const float* __restrict__ Wb4, const float* __restrict__ bb4, float* __restrict__ wsf)
{
    __shared__ float red[256];
    const float* hb3 = wsf + WS_HB3;
    float* Bten = wsf + WS_BTEN;
    int tid = threadIdx.x;
    int ol = tid & 15, part = tid >> 4;          // 16 outputs/block, 16 hh-parts of 128
    int o = blockIdx.x * 16 + ol;
    float a = 0.0f;
    for (int q = 0; q < 128; ++q) {
        int hh = part*128 + q;
        a = fmaf(hb3[hh], Wb4[(size_t)hh*4096 + o], a);
    }
    red[part*16 + ol] = a;
    __syncthreads();
    for (int s = 8; s >= 1; s >>= 1) {
        if (part < s) red[part*16+ol] += red[(part+s)*16+ol];
        __syncthreads();
    }
    if (tid < 16) {
        float v = red[tid] + bb4[blockIdx.x*16 + tid];
        Bten[blockIdx.x*16 + tid] = leakyf(v);
    }
}

// ================= K3: encoder -> zs slab 0 (z0) =====================================
__global__ void __launch_bounds__(256) k_encoder(
    const float* __restrict__ n0,
    const float* __restrict__ We1, const float* __restrict__ be1,
    const float* __restrict__ We2, const float* __restrict__ be2,
    float* __restrict__ zs)
{
    __shared__ float hL[8][88];
    int tid = threadIdx.x;
    int r = tid >> 5, c = tid & 31;
    int row = blockIdx.x * 8 + r;
    const float* nrow = n0 + (size_t)row * 466;
    int c2 = (c + 64 < 86) ? (c + 64) : 85;      // clamp (discarded if invalid)
    float a0 = 0.f, a1 = 0.f, a2 = 0.f;
    for (int n = 0; n < 466; ++n) {
        float nv = nrow[n];
        a0 = fmaf(nv, We1[n*86 + c], a0);
        a1 = fmaf(nv, We1[n*86 + c + 32], a1);
        a2 = fmaf(nv, We1[n*86 + c2], a2);
    }
    hL[r][c]      = leakyf(a0 + be1[c]);
    hL[r][c + 32] = leakyf(a1 + be1[c + 32]);
    if (c < 22) hL[r][c + 64] = leakyf(a2 + be1[c + 64]);
    __syncthreads();
    if (tid < 128) {
        int r2 = tid >> 4, ii = tid & 15;
        int row2 = blockIdx.x * 8 + r2;
        float a = be2[ii];
        #pragma unroll
        for (int hh = 0; hh < 86; ++hh) a = fmaf(hL[r2][hh], We2[hh*16 + ii], a);
        zs[(size_t)row2 * 16 + ii] = a;          // NO leaky on z0
    }
}

// ================= K4: Dopri5 solver (non-cooperative; slot barrier) =================
// 256 blocks x 256 threads, guaranteed co-resident (256 CUs; <=2 blocks/CU still fits).
// Mapping/reductions FROZEN (bit-exactness): 2 threads per (b,i), 8+8 k-split,
// butterfly bsum, 256-slot gsum. v_pk_fma_f32 packs the 16 independent tmp chains
// pairwise — identical per-chain order, half the FMA issue slots.
__global__ void __launch_bounds__(256) k_solver(
    const float* __restrict__ tstep, float* __restrict__ wsf)
{
    __shared__ float zL[8][16];
    __shared__ float redA[4], redB[4];
    float* Amat = wsf + WS_AMAT;
    float* Bten = wsf + WS_BTEN;
    float* zs   = wsf + WS_ZS;
    unsigned long long* slots = (unsigned long long*)(wsf + WS_SLOTSF);

    const int tid = threadIdx.x, blk = blockIdx.x;
    const int e = tid >> 5, g = tid & 31;
    const int i = g >> 1, h = g & 1, h8 = h * 8;
    const int b = blk * 8 + e;

    // --- per-thread constants: B half-slice as jj-pairs (v2f), A row pairs ---
    v2f Bl2[64], aR2[8];
    #pragma unroll
    for (int p = 0; p < 8; ++p) {
        int jA = (h8 + 2*p)     & 15;
        int jB = (h8 + 2*p + 1) & 15;
        v2f ap; ap.x = (h == 0) ? Amat[i*16 + 2*p] : 0.0f;
        ap.y = (h == 0) ? Amat[i*16 + 2*p + 1] : 0.0f;
        aR2[p] = ap;
        const float4* bpA = (const float4*)(Bten + i*256 + jA*16 + h8);
        const float4* bpB = (const float4*)(Bten + i*256 + jB*16 + h8);
        float4 a0 = bpA[0], a1 = bpA[1], b0 = bpB[0], b1 = bpB[1];
        v2f q;
        q.x=a0.x; q.y=b0.x; Bl2[p*8+0]=q;  q.x=a0.y; q.y=b0.y; Bl2[p*8+1]=q;
        q.x=a0.z; q.y=b0.z; Bl2[p*8+2]=q;  q.x=a0.w; q.y=b0.w; Bl2[p*8+3]=q;
        q.x=a1.x; q.y=b1.x; Bl2[p*8+4]=q;  q.x=a1.y; q.y=b1.y; Bl2[p*8+5]=q;
        q.x=a1.z; q.y=b1.z; Bl2[p*8+6]=q;  q.x=a1.w; q.y=b1.w; Bl2[p*8+7]=q;
    }

    float y = zs[(size_t)b*16 + i];

    auto feval = [&](float zi) -> float {
        zL[e][i] = zi;                                // both h lanes write same value
        const float4* zp = (const float4*)(&zL[e][0]);
        int q0 = h8 >> 2;                             // rotated read: zz[m]=z[(h8+m)&15]
        float4 r0 = zp[q0], r1 = zp[(q0+1)&3], r2 = zp[(q0+2)&3], r3 = zp[(q0+3)&3];
        float zz[16] = { r0.x,r0.y,r0.z,r0.w, r1.x,r1.y,r1.z,r1.w,
                         r2.x,r2.y,r2.z,r2.w, r3.x,r3.y,r3.z,r3.w };
        v2f zb[8];
        #pragma unroll
        for (int kk = 0; kk < 8; ++kk) { v2f t; t.x = zz[kk]; t.y = zz[kk]; zb[kk] = t; }
        v2f t2[8];
        #pragma unroll
        for (int p = 0; p < 8; ++p) t2[p] = aR2[p];
        #pragma unroll
        for (int p = 0; p < 8; ++p) {
            #pragma unroll
            for (int kk = 0; kk < 8; ++kk)
                asm("v_pk_fma_f32 %0, %1, %2, %0" : "+v"(t2[p]) : "v"(Bl2[p*8+kk]), "v"(zb[kk]));
        }
        float acc = 0.0f;
        #pragma unroll
        for (int p = 0; p < 8; ++p) {
            acc = fmaf(zz[2*p],     t2[p].x, acc);
            acc = fmaf(zz[2*p + 1], t2[p].y, acc);
        }
        acc += __shfl_xor(acc, 1);                    // combine the two k-halves
        return acc;
    };

    float dt = (tstep[1] - tstep[0]) * 0.3f;
    float k1 = feval(y), k2, k3, k4, k5, k6, k7;
    int stepIdx = 0;

    for (int iv = 0; iv < 31; ++iv) {
        float t  = tstep[iv];
        float t1 = tstep[iv + 1];
        for (int it = 0; it < 16; ++it) {
            if (t >= t1 - 1e-10f) break;              // 'done' iterations are exact no-ops
            float dtc = fminf(dt, t1 - t);

            float z2 = fmaf(dtc, cA21*k1, y);                                         k2 = feval(z2);
            float z3 = fmaf(dtc, fmaf(cA32,k2, cA31*k1), y);                          k3 = feval(z3);
            float z4 = fmaf(dtc, fmaf(cA43,k3, fmaf(cA42,k2, cA41*k1)), y);           k4 = feval(z4);
            float z5 = fmaf(dtc, fmaf(cA54,k4, fmaf(cA53,k3, fmaf(cA52,k2, cA51*k1))), y);
            k5 = feval(z5);
            float z6 = fmaf(dtc, fmaf(cA65,k5, fmaf(cA64,k4, fmaf(cA63,k3, fmaf(cA62,k2, cA61*k1)))), y);
            k6 = feval(z6);
            float y5 = fmaf(dtc, fmaf(cB6,k6, fmaf(cB5,k5, fmaf(cB4,k4, fmaf(cB3,k3, cB1*k1)))), y);
            k7 = feval(y5);
            float err = dtc * fmaf(cE7,k7, fmaf(cE6,k6, fmaf(cE5,k5, fmaf(cE4,k4, fmaf(cE3,k3, cE1*k1)))));

            float ay = fabsf(y), a5 = fabsf(y5);
            float mx = (ay > a5) ? ay : a5;           // NaN-propagating max (matches jnp)
            float tol = fmaf(1e-5f, mx, 1e-20f);
            float r = err / tol;
            float r2 = r * r;

            // ---- block partial sum (h-duplicated; divide by 65536 at the end) ----
            float w = r2;
            w += __shfl_xor(w, 1);  w += __shfl_xor(w, 2);  w += __shfl_xor(w, 4);
            w += __shfl_xor(w, 8);  w += __shfl_xor(w, 16); w += __shfl_xor(w, 32);
            if ((tid & 63) == 0) redA[tid >> 6] = w;
            __syncthreads();
            float bsum = ((redA[0] + redA[1]) + redA[2]) + redA[3];
            __syncthreads();

            // ---- decentralized grid barrier: value-carrying 64-bit slots ----
            unsigned long long* rowp = slots + (size_t)stepIdx * 256;
            if (tid == 0) {
                unsigned long long pv = (1ull << 32) | (unsigned long long)__float_as_uint(bsum);
                __hip_atomic_store(&rowp[blk], pv, __ATOMIC_RELAXED, __HIP_MEMORY_SCOPE_AGENT);
            }
            unsigned long long v = __hip_atomic_load(&rowp[tid], __ATOMIC_RELAXED, __HIP_MEMORY_SCOPE_AGENT);
            while ((unsigned)(v >> 32) != 1u) {
                __builtin_amdgcn_s_sleep(1);
                v = __hip_atomic_load(&rowp[tid], __ATOMIC_RELAXED, __HIP_MEMORY_SCOPE_AGENT);
            }
            float ps = __uint_as_float((unsigned)v);
            ps += __shfl_xor(ps, 1);  ps += __shfl_xor(ps, 2);  ps += __shfl_xor(ps, 4);
            ps += __shfl_xor(ps, 8);  ps += __shfl_xor(ps, 16); ps += __shfl_xor(ps, 32);
            if ((tid & 63) == 0) redB[tid >> 6] = ps;
            __syncthreads();
            float gsum = ((redB[0] + redB[1]) + redB[2]) + redB[3];
            __syncthreads();
            ++stepIdx;

            float en = sqrtf(gsum * (1.0f / 65536.0f));   // /65536: h-dup (x2) * mean (/32768)

            if (!(en == en)) {
                // NaN controller state is a fixed point of the reference: y frozen forever.
                if (h == 0) {
                    for (int s = iv + 1; s < 32; ++s)
                        zs[((size_t)s * 2048 + b) * 16 + i] = y;
                }
                return;
            }
            if (en <= 1.0f) { t = t + dtc; y = y5; k1 = k7; }   // accept (+FSAL)
            float fac = 0.9f * powf(fmaxf(en, 1e-12f), -0.2f);
            fac = fminf(fmaxf(fac, 0.2f), 10.0f);
            dt = dt * fac;
        }
        if (h == 0) zs[((size_t)(iv + 1) * 2048 + b) * 16 + i] = y;
    }
}

// ================= K5: decoder  out = leaky(zs@Wd1+bd1)@Wd2 + bd2 ====================
// 8 rows/block. Phase 1: hL[8][86] into LDS. Phase 2: lanes sweep columns c →
// coalesced Wd2 loads + coalesced out stores; hL broadcast from LDS. Per-output
// fmaf chain order identical to the reference mapping (hh ascending).
__global__ void __launch_bounds__(256) k_decoder(
    const float* __restrict__ zs,
    const float* __restrict__ Wd1, const float* __restrict__ bd1,
    const float* __restrict__ Wd2, const float* __restrict__ bd2,
    float* __restrict__ out)
{
    __shared__ float hL[8][86];
    int tid = threadIdx.x;
    size_t rowbase = (size_t)blockIdx.x * 8;

    for (int v = tid; v < 688; v += 256) {
        int r = v / 86, hh = v - r * 86;
        const float* zr = zs + (rowbase + r) * 16;
        float a = bd1[hh];
        #pragma unroll
        for (int ii = 0; ii < 16; ++ii) a = fmaf(zr[ii], Wd1[ii*86 + hh], a);
        hL[r][hh] = leakyf(a);
    }
    __syncthreads();

    for (int c = tid; c < 466; c += 256) {
        float acc[8];
        #pragma unroll
        for (int r = 0; r < 8; ++r) acc[r] = bd2[c];
        for (int hh = 0; hh < 86; ++hh) {
            float w = Wd2[hh*466 + c];
            #pragma unroll
            for (int r = 0; r < 8; ++r) acc[r] = fmaf(hL[r][hh], w, acc[r]);
        }
        #pragma unroll
        for (int r = 0; r < 8; ++r) out[(rowbase + r) * 466 + c] = acc[r];
    }
}

// ====================================================================================
extern "C" void kernel_launch(void* const* d_in, const int* in_sizes, int n_in,
                              void* d_out, int out_size, void* d_ws, size_t ws_size,
                              hipStream_t stream)
{
    const float* n0   = (const float*)d_in[0];
    const float* p    = (const float*)d_in[1];
    const float* tstep= (const float*)d_in[2];
    const float* We1  = (const float*)d_in[3];  const float* be1 = (const float*)d_in[4];
    const float* We2  = (const float*)d_in[5];  const float* be2 = (const float*)d_in[6];
    const float* Wd1  = (const float*)d_in[7];  const float* bd1 = (const float*)d_in[8];
    const float* Wd2  = (const float*)d_in[9];  const float* bd2 = (const float*)d_in[10];
    const float* Wa1  = (const float*)d_in[11]; const float* ba1 = (const float*)d_in[12];
    const float* Wa2  = (const float*)d_in[13]; const float* ba2 = (const float*)d_in[14];
    const float* Wa3  = (const float*)d_in[15]; const float* ba3 = (const float*)d_in[16];
    const float* Wb1  = (const float*)d_in[17]; const float* bb1 = (const float*)d_in[18];
    const float* Wb2  = (const float*)d_in[19]; const float* bb2 = (const float*)d_in[20];
    const float* Wb3  = (const float*)d_in[21]; const float* bb3 = (const float*)d_in[22];
    const float* Wb4  = (const float*)d_in[23]; const float* bb4 = (const float*)d_in[24];
    float* out = (float*)d_out;
    float* wsf = (float*)d_ws;

    hipLaunchKernelGGL(k_smallnets, dim3(1), dim3(256), 0, stream,
                       p, Wa1, ba1, Wa2, ba2, Wa3, ba3, Wb1, bb1, Wb2, bb2, Wb3, bb3, wsf);
    hipLaunchKernelGGL(k_bten, dim3(256), dim3(256), 0, stream, Wb4, bb4, wsf);
    hipLaunchKernelGGL(k_encoder, dim3(256), dim3(256), 0, stream,
                       n0, We1, be1, We2, be2, wsf + WS_ZS);

    // regular launch: 256 blocks <= 256 CUs -> co-resident; slot barrier is one-shot
    hipLaunchKernelGGL(k_solver, dim3(256), dim3(256), 0, stream, tstep, wsf);

    hipLaunchKernelGGL(k_decoder, dim3(8192), dim3(256), 0, stream,
                       wsf + WS_ZS, Wd1, bd1, Wd2, bd2, out);
}

// Round 3
// 1517.281 us; speedup vs baseline: 1.2999x; 1.0873x over previous
//
#include <hip/hip_runtime.h>
#include <cmath>

#define DEV __device__ __forceinline__

static DEV float leakyf(float x){ return x >= 0.0f ? x : 0.2f*x; }

typedef float v2f __attribute__((ext_vector_type(2)));

// ---------------- Dopri5 tableau ----------------
constexpr float cA21 = (float)(1.0/5.0);
constexpr float cA31 = (float)(3.0/40.0),  cA32 = (float)(9.0/40.0);
constexpr float cA41 = (float)(44.0/45.0), cA42 = (float)(-56.0/15.0), cA43 = (float)(32.0/9.0);
constexpr float cA51 = (float)(19372.0/6561.0), cA52 = (float)(-25360.0/2187.0);
constexpr float cA53 = (float)(64448.0/6561.0), cA54 = (float)(-212.0/729.0);
constexpr float cA61 = (float)(9017.0/3168.0),  cA62 = (float)(-355.0/33.0);
constexpr float cA63 = (float)(46732.0/5247.0), cA64 = (float)(49.0/176.0);
constexpr float cA65 = (float)(-5103.0/18656.0);
constexpr float cB1 = (float)(35.0/384.0),  cB3 = (float)(500.0/1113.0), cB4 = (float)(125.0/192.0);
constexpr float cB5 = (float)(-2187.0/6784.0), cB6 = (float)(11.0/84.0);
constexpr float cE1 = (float)(71.0/57600.0), cE3 = (float)(-71.0/16695.0), cE4 = (float)(71.0/1920.0);
constexpr float cE5 = (float)(-17253.0/339200.0), cE6 = (float)(22.0/525.0), cE7 = (float)(-1.0/40.0);

// ---------------- workspace layout (float indices into d_ws) ----------------
#define WS_AMAT   0                      // 256 floats   : A(p) 16x16 (leaky applied)
#define WS_HB3    256                    // 2048 floats  : B-net hidden 3
#define WS_BTEN   2304                   // 4096 floats  : B(p) 16x16x16 (leaky applied)
#define WS_ZS     6400                   // 32*2048*16 = 1048576 floats : z trajectory
#define WS_SLOTSF (6400 + 1048576)       // 496*256 u64 barrier slots = 253952 floats

// ================= K1: tiny MLPs (A-net fully; B-net through hb3) — 1 block ==========
__global__ void __launch_bounds__(256) k_smallnets(
    const float* __restrict__ p,
    const float* __restrict__ Wa1, const float* __restrict__ ba1,
    const float* __restrict__ Wa2, const float* __restrict__ ba2,
    const float* __restrict__ Wa3, const float* __restrict__ ba3,
    const float* __restrict__ Wb1, const float* __restrict__ bb1,
    const float* __restrict__ Wb2, const float* __restrict__ bb2,
    const float* __restrict__ Wb3, const float* __restrict__ bb3,
    float* __restrict__ wsf)
{
    __shared__ float sp[4], sa1[16], sa2[128], sb1[16], sb2[64];
    int tid = threadIdx.x;
    if (tid < 4) sp[tid] = p[tid];
    __syncthreads();
    if (tid < 16) {
        float a = ba1[tid];
        for (int j = 0; j < 4; ++j) a = fmaf(sp[j], Wa1[j*16+tid], a);
        sa1[tid] = leakyf(a);
        float c = bb1[tid];
        for (int j = 0; j < 4; ++j) c = fmaf(sp[j], Wb1[j*16+tid], c);
        sb1[tid] = leakyf(c);
    }
    __syncthreads();
    if (tid < 128) {
        float a = ba2[tid];
        for (int j = 0; j < 16; ++j) a = fmaf(sa1[j], Wa2[j*128+tid], a);
        sa2[tid] = leakyf(a);
    }
    if (tid < 64) {
        float c = bb2[tid];
        for (int j = 0; j < 16; ++j) c = fmaf(sb1[j], Wb2[j*64+tid], c);
        sb2[tid] = leakyf(c);
    }
    __syncthreads();
    {   // Amat: 256 outputs
        float a = ba3[tid];
        for (int j = 0; j < 128; ++j) a = fmaf(sa2[j], Wa3[j*256+tid], a);
        wsf[WS_AMAT + tid] = leakyf(a);
    }
    for (int q = 0; q < 8; ++q) {        // hb3: 2048 outputs
        int o = q*256 + tid;
        float c = bb3[o];
        for (int j = 0; j < 64; ++j) c = fmaf(sb2[j], Wb3[j*2048+o], c);
        wsf[WS_HB3 + o] = leakyf(c);
    }
}

// ================= K2: Bten = leaky(hb3 @ Wb4 + bb4) — HBM-bound (33.5 MB) ==========
__global__ void __launch_bounds__(256) k_bten(
    const float* __restrict__ Wb4, const float* __restrict__ bb4, float* __restrict__ wsf)
{
    __shared__ float red[256];
    const float* hb3 = wsf + WS_HB3;
    float* Bten = wsf + WS_BTEN;
    int tid = threadIdx.x;
    int ol = tid & 15, part = tid >> 4;          // 16 outputs/block, 16 hh-parts of 128
    int o = blockIdx.x * 16 + ol;
    float a = 0.0f;
    for (int q = 0; q < 128; ++q) {
        int hh = part*128 + q;
        a = fmaf(hb3[hh], Wb4[(size_t)hh*4096 + o], a);
    }
    red[part*16 + ol] = a;
    __syncthreads();
    for (int s = 8; s >= 1; s >>= 1) {
        if (part < s) red[part*16+ol] += red[(part+s)*16+ol];
        __syncthreads();
    }
    if (tid < 16) {
        float v = red[tid] + bb4[blockIdx.x*16 + tid];
        Bten[blockIdx.x*16 + tid] = leakyf(v);
    }
}

// ================= K3: encoder -> zs slab 0 (z0) =====================================
__global__ void __launch_bounds__(256) k_encoder(
    const float* __restrict__ n0,
    const float* __restrict__ We1, const float* __restrict__ be1,
    const float* __restrict__ We2, const float* __restrict__ be2,
    float* __restrict__ zs)
{
    __shared__ float hL[8][88];
    int tid = threadIdx.x;
    int r = tid >> 5, c = tid & 31;
    int row = blockIdx.x * 8 + r;
    const float* nrow = n0 + (size_t)row * 466;
    int c2 = (c + 64 < 86) ? (c + 64) : 85;      // clamp (discarded if invalid)
    float a0 = 0.f, a1 = 0.f, a2 = 0.f;
    for (int n = 0; n < 466; ++n) {
        float nv = nrow[n];
        a0 = fmaf(nv, We1[n*86 + c], a0);
        a1 = fmaf(nv, We1[n*86 + c + 32], a1);
        a2 = fmaf(nv, We1[n*86 + c2], a2);
    }
    hL[r][c]      = leakyf(a0 + be1[c]);
    hL[r][c + 32] = leakyf(a1 + be1[c + 32]);
    if (c < 22) hL[r][c + 64] = leakyf(a2 + be1[c + 64]);
    __syncthreads();
    if (tid < 128) {
        int r2 = tid >> 4, ii = tid & 15;
        int row2 = blockIdx.x * 8 + r2;
        float a = be2[ii];
        #pragma unroll
        for (int hh = 0; hh < 86; ++hh) a = fmaf(hL[r2][hh], We2[hh*16 + ii], a);
        zs[(size_t)row2 * 16 + ii] = a;          // NO leaky on z0
    }
}

// ================= K4: Dopri5 solver (non-cooperative; slot barrier) =================
// 256 blocks x 256 threads, co-resident on 256 CUs. FROZEN arithmetic (bit-exact draw):
// 2 threads per (b,i), 8+8 k-split, pk-fma pairs, butterfly bsum, 256-slot gsum.
// R3 changes (latency only, bit-safe): (a) parity double-buffered redA/redB removes
// 2 of 4 per-step __syncthreads; (b) poll loop keeps 2 outstanding loads, no s_sleep
// — halves retry granularity on the cross-XCD slot visibility wait.
__global__ void __launch_bounds__(256) k_solver(
    const float* __restrict__ tstep, float* __restrict__ wsf)
{
    __shared__ float zL[8][16];
    __shared__ float redA[2][4], redB[2][4];
    float* Amat = wsf + WS_AMAT;
    float* Bten = wsf + WS_BTEN;
    float* zs   = wsf + WS_ZS;
    unsigned long long* slots = (unsigned long long*)(wsf + WS_SLOTSF);

    const int tid = threadIdx.x, blk = blockIdx.x;
    const int e = tid >> 5, g = tid & 31;
    const int i = g >> 1, h = g & 1, h8 = h * 8;
    const int b = blk * 8 + e;

    // --- per-thread constants: B half-slice as jj-pairs (v2f), A row pairs ---
    v2f Bl2[64], aR2[8];
    #pragma unroll
    for (int p = 0; p < 8; ++p) {
        int jA = (h8 + 2*p)     & 15;
        int jB = (h8 + 2*p + 1) & 15;
        v2f ap; ap.x = (h == 0) ? Amat[i*16 + 2*p] : 0.0f;
        ap.y = (h == 0) ? Amat[i*16 + 2*p + 1] : 0.0f;
        aR2[p] = ap;
        const float4* bpA = (const float4*)(Bten + i*256 + jA*16 + h8);
        const float4* bpB = (const float4*)(Bten + i*256 + jB*16 + h8);
        float4 a0 = bpA[0], a1 = bpA[1], b0 = bpB[0], b1 = bpB[1];
        v2f q;
        q.x=a0.x; q.y=b0.x; Bl2[p*8+0]=q;  q.x=a0.y; q.y=b0.y; Bl2[p*8+1]=q;
        q.x=a0.z; q.y=b0.z; Bl2[p*8+2]=q;  q.x=a0.w; q.y=b0.w; Bl2[p*8+3]=q;
        q.x=a1.x; q.y=b1.x; Bl2[p*8+4]=q;  q.x=a1.y; q.y=b1.y; Bl2[p*8+5]=q;
        q.x=a1.z; q.y=b1.z; Bl2[p*8+6]=q;  q.x=a1.w; q.y=b1.w; Bl2[p*8+7]=q;
    }

    float y = zs[(size_t)b*16 + i];

    auto feval = [&](float zi) -> float {
        zL[e][i] = zi;                                // both h lanes write same value
        const float4* zp = (const float4*)(&zL[e][0]);
        int q0 = h8 >> 2;                             // rotated read: zz[m]=z[(h8+m)&15]
        float4 r0 = zp[q0], r1 = zp[(q0+1)&3], r2 = zp[(q0+2)&3], r3 = zp[(q0+3)&3];
        float zz[16] = { r0.x,r0.y,r0.z,r0.w, r1.x,r1.y,r1.z,r1.w,
                         r2.x,r2.y,r2.z,r2.w, r3.x,r3.y,r3.z,r3.w };
        v2f zb[8];
        #pragma unroll
        for (int kk = 0; kk < 8; ++kk) { v2f t; t.x = zz[kk]; t.y = zz[kk]; zb[kk] = t; }
        v2f t2[8];
        #pragma unroll
        for (int p = 0; p < 8; ++p) t2[p] = aR2[p];
        #pragma unroll
        for (int p = 0; p < 8; ++p) {
            #pragma unroll
            for (int kk = 0; kk < 8; ++kk)
                asm("v_pk_fma_f32 %0, %1, %2, %0" : "+v"(t2[p]) : "v"(Bl2[p*8+kk]), "v"(zb[kk]));
        }
        float acc = 0.0f;
        #pragma unroll
        for (int p = 0; p < 8; ++p) {
            acc = fmaf(zz[2*p],     t2[p].x, acc);
            acc = fmaf(zz[2*p + 1], t2[p].y, acc);
        }
        acc += __shfl_xor(acc, 1);                    // combine the two k-halves
        return acc;
    };

    float dt = (tstep[1] - tstep[0]) * 0.3f;
    float k1 = feval(y), k2, k3, k4, k5, k6, k7;
    int stepIdx = 0;

    for (int iv = 0; iv < 31; ++iv) {
        float t  = tstep[iv];
        float t1 = tstep[iv + 1];
        for (int it = 0; it < 16; ++it) {
            if (t >= t1 - 1e-10f) break;              // 'done' iterations are exact no-ops
            float dtc = fminf(dt, t1 - t);

            float z2 = fmaf(dtc, cA21*k1, y);                                         k2 = feval(z2);
            float z3 = fmaf(dtc, fmaf(cA32,k2, cA31*k1), y);                          k3 = feval(z3);
            float z4 = fmaf(dtc, fmaf(cA43,k3, fmaf(cA42,k2, cA41*k1)), y);           k4 = feval(z4);
            float z5 = fmaf(dtc, fmaf(cA54,k4, fmaf(cA53,k3, fmaf(cA52,k2, cA51*k1))), y);
            k5 = feval(z5);
            float z6 = fmaf(dtc, fmaf(cA65,k5, fmaf(cA64,k4, fmaf(cA63,k3, fmaf(cA62,k2, cA61*k1)))), y);
            k6 = feval(z6);
            float y5 = fmaf(dtc, fmaf(cB6,k6, fmaf(cB5,k5, fmaf(cB4,k4, fmaf(cB3,k3, cB1*k1)))), y);
            k7 = feval(y5);
            float err = dtc * fmaf(cE7,k7, fmaf(cE6,k6, fmaf(cE5,k5, fmaf(cE4,k4, fmaf(cE3,k3, cE1*k1)))));

            float ay = fabsf(y), a5 = fabsf(y5);
            float mx = (ay > a5) ? ay : a5;           // NaN-propagating max (matches jnp)
            float tol = fmaf(1e-5f, mx, 1e-20f);
            float r = err / tol;
            float r2 = r * r;

            const int par = stepIdx & 1;

            // ---- block partial sum (h-duplicated; divide by 65536 at the end) ----
            float w = r2;
            w += __shfl_xor(w, 1);  w += __shfl_xor(w, 2);  w += __shfl_xor(w, 4);
            w += __shfl_xor(w, 8);  w += __shfl_xor(w, 16); w += __shfl_xor(w, 32);
            if ((tid & 63) == 0) redA[par][tid >> 6] = w;
            __syncthreads();
            float bsum = ((redA[par][0] + redA[par][1]) + redA[par][2]) + redA[par][3];

            // ---- decentralized grid barrier: value-carrying 64-bit slots ----
            unsigned long long* rowp = slots + (size_t)stepIdx * 256;
            if (tid == 0) {
                unsigned long long pv = (1ull << 32) | (unsigned long long)__float_as_uint(bsum);
                __hip_atomic_store(&rowp[blk], pv, __ATOMIC_RELAXED, __HIP_MEMORY_SCOPE_AGENT);
            }
            unsigned long long v = __hip_atomic_load(&rowp[tid], __ATOMIC_RELAXED, __HIP_MEMORY_SCOPE_AGENT);
            if ((unsigned)(v >> 32) != 1u) {
                for (;;) {
                    unsigned long long va = __hip_atomic_load(&rowp[tid], __ATOMIC_RELAXED, __HIP_MEMORY_SCOPE_AGENT);
                    unsigned long long vb = __hip_atomic_load(&rowp[tid], __ATOMIC_RELAXED, __HIP_MEMORY_SCOPE_AGENT);
                    if ((unsigned)(va >> 32) == 1u) { v = va; break; }
                    if ((unsigned)(vb >> 32) == 1u) { v = vb; break; }
                }
            }
            float ps = __uint_as_float((unsigned)v);
            ps += __shfl_xor(ps, 1);  ps += __shfl_xor(ps, 2);  ps += __shfl_xor(ps, 4);
            ps += __shfl_xor(ps, 8);  ps += __shfl_xor(ps, 16); ps += __shfl_xor(ps, 32);
            if ((tid & 63) == 0) redB[par][tid >> 6] = ps;
            __syncthreads();
            float gsum = ((redB[par][0] + redB[par][1]) + redB[par][2]) + redB[par][3];
            ++stepIdx;

            float en = sqrtf(gsum * (1.0f / 65536.0f));   // /65536: h-dup (x2) * mean (/32768)

            if (!(en == en)) {
                // NaN controller state is a fixed point of the reference: y frozen forever.
                if (h == 0) {
                    for (int s = iv + 1; s < 32; ++s)
                        zs[((size_t)s * 2048 + b) * 16 + i] = y;
                }
                return;
            }
            if (en <= 1.0f) { t = t + dtc; y = y5; k1 = k7; }   // accept (+FSAL)
            float fac = 0.9f * powf(fmaxf(en, 1e-12f), -0.2f);
            fac = fminf(fmaxf(fac, 0.2f), 10.0f);
            dt = dt * fac;
        }
        if (h == 0) zs[((size_t)(iv + 1) * 2048 + b) * 16 + i] = y;
    }
}

// ================= K5: decoder  out = leaky(zs@Wd1+bd1)@Wd2 + bd2 ====================
// 8 rows/block. Phase 1: hL[8][86] into LDS. Phase 2: lanes sweep columns c →
// coalesced Wd2 loads + coalesced out stores; hL broadcast from LDS. Per-output
// fmaf chain order identical to the reference mapping (hh ascending).
__global__ void __launch_bounds__(256) k_decoder(
    const float* __restrict__ zs,
    const float* __restrict__ Wd1, const float* __restrict__ bd1,
    const float* __restrict__ Wd2, const float* __restrict__ bd2,
    float* __restrict__ out)
{
    __shared__ float hL[8][86];
    int tid = threadIdx.x;
    size_t rowbase = (size_t)blockIdx.x * 8;

    for (int v = tid; v < 688; v += 256) {
        int r = v / 86, hh = v - r * 86;
        const float* zr = zs + (rowbase + r) * 16;
        float a = bd1[hh];
        #pragma unroll
        for (int ii = 0; ii < 16; ++ii) a = fmaf(zr[ii], Wd1[ii*86 + hh], a);
        hL[r][hh] = leakyf(a);
    }
    __syncthreads();

    for (int c = tid; c < 466; c += 256) {
        float acc[8];
        #pragma unroll
        for (int r = 0; r < 8; ++r) acc[r] = bd2[c];
        for (int hh = 0; hh < 86; ++hh) {
            float w = Wd2[hh*466 + c];
            #pragma unroll
            for (int r = 0; r < 8; ++r) acc[r] = fmaf(hL[r][hh], w, acc[r]);
        }
        #pragma unroll
        for (int r = 0; r < 8; ++r) out[(rowbase + r) * 466 + c] = acc[r];
    }
}

// ====================================================================================
extern "C" void kernel_launch(void* const* d_in, const int* in_sizes, int n_in,
                              void* d_out, int out_size, void* d_ws, size_t ws_size,
                              hipStream_t stream)
{
    const float* n0   = (const float*)d_in[0];
    const float* p    = (const float*)d_in[1];
    const float* tstep= (const float*)d_in[2];
    const float* We1  = (const float*)d_in[3];  const float* be1 = (const float*)d_in[4];
    const float* We2  = (const float*)d_in[5];  const float* be2 = (const float*)d_in[6];
    const float* Wd1  = (const float*)d_in[7];  const float* bd1 = (const float*)d_in[8];
    const float* Wd2  = (const float*)d_in[9];  const float* bd2 = (const float*)d_in[10];
    const float* Wa1  = (const float*)d_in[11]; const float* ba1 = (const float*)d_in[12];
    const float* Wa2  = (const float*)d_in[13]; const float* ba2 = (const float*)d_in[14];
    const float* Wa3  = (const float*)d_in[15]; const float* ba3 = (const float*)d_in[16];
    const float* Wb1  = (const float*)d_in[17]; const float* bb1 = (const float*)d_in[18];
    const float* Wb2  = (const float*)d_in[19]; const float* bb2 = (const float*)d_in[20];
    const float* Wb3  = (const float*)d_in[21]; const float* bb3 = (const float*)d_in[22];
    const float* Wb4  = (const float*)d_in[23]; const float* bb4 = (const float*)d_in[24];
    float* out = (float*)d_out;
    float* wsf = (float*)d_ws;

    hipLaunchKernelGGL(k_smallnets, dim3(1), dim3(256), 0, stream,
                       p, Wa1, ba1, Wa2, ba2, Wa3, ba3, Wb1, bb1, Wb2, bb2, Wb3, bb3, wsf);
    hipLaunchKernelGGL(k_bten, dim3(256), dim3(256), 0, stream, Wb4, bb4, wsf);
    hipLaunchKernelGGL(k_encoder, dim3(256), dim3(256), 0, stream,
                       n0, We1, be1, We2, be2, wsf + WS_ZS);

    // regular launch: 256 blocks <= 256 CUs -> co-resident; slot barrier is one-shot
    hipLaunchKernelGGL(k_solver, dim3(256), dim3(256), 0, stream, tstep, wsf);

    hipLaunchKernelGGL(k_decoder, dim3(8192), dim3(256), 0, stream,
                       wsf + WS_ZS, Wd1, bd1, Wd2, bd2, out);
}